// Round 3
// baseline (395.467 us; speedup 1.0000x reference)
//
#include <hip/hip_runtime.h>

#define BOX 71
#define NF 32
#define MAX_DIST_F 35.0f

// Output: [B=8, 71,71,71, F=32] fp32 = 91,625,216 floats = 366,500,864 bytes.
// Reference scatters EVERY batch into batch slice 0 => slices 1..7 are always
// all-zero, and all atomics land in the first 45.8 MB.
#define SLICE_FLOATS (BOX * BOX * BOX * NF)        // 11,453,152
#define TOTAL_FLOATS (8 * SLICE_FLOATS)            // 91,625,216
#define TOTAL_F4     (TOTAL_FLOATS / 4)            // 22,906,304
#define SLICE0_F4    (SLICE_FLOATS / 4)            //  2,863,288

// Native vector type: __builtin_nontemporal_store rejects HIP_vector_type
// (class), accepts clang ext_vector types.
typedef float f32x4 __attribute__((ext_vector_type(4)));

// Zero the whole output. Slice 0 with regular stores (dirty lines stay in
// L2/L3 -> subsequent atomic RMWs hit cache). Slices 1..7 with nontemporal
// stores (pure streaming writes, don't evict slice 0).
__global__ __launch_bounds__(256) void zero_grid(f32x4* __restrict__ out)
{
    const f32x4 z = {0.f, 0.f, 0.f, 0.f};
    int stride = gridDim.x * blockDim.x;
    for (int i = blockIdx.x * blockDim.x + threadIdx.x; i < TOTAL_F4; i += stride) {
        if (i < SLICE0_F4) {
            out[i] = z;
        } else {
            __builtin_nontemporal_store(z, out + i);
        }
    }
}

// One 32-lane group per point: lane f handles feature f.
// features layout [B,N,F] -> consecutive lanes read consecutive floats (coalesced).
// atomicAdd target grid[0, x, y, z, f] -> 32 consecutive floats per point (coalesced burst).
__global__ __launch_bounds__(256) void MakeGrid_scatter_kernel(
    const float* __restrict__ coords,
    const float* __restrict__ features,
    float* __restrict__ grid,
    int total_points)
{
    int t = blockIdx.x * blockDim.x + threadIdx.x;
    int p = t >> 5;          // point index
    int f = t & 31;          // feature index
    if (p >= total_points) return;

    // All 32 lanes of the group load the same 3 coords (L1-cached broadcast).
    float cx = coords[p * 3 + 0];
    float cy = coords[p * 3 + 1];
    float cz = coords[p * 3 + 2];

    // jnp.round = round-half-to-even; rintf matches (default RNE rounding mode).
    // GRID_RES = 1.0 so (c + 35.0f) / 1.0f == c + 35.0f exactly.
    float rx = rintf(cx + MAX_DIST_F);
    float ry = rintf(cy + MAX_DIST_F);
    float rz = rintf(cz + MAX_DIST_F);
    int gx = (int)rx;
    int gy = (int)ry;
    int gz = (int)rz;

    bool in_box = (gx >= 0) & (gx < BOX) &
                  (gy >= 0) & (gy < BOX) &
                  (gz >= 0) & (gz < BOX);
    if (!in_box) return;     // reference adds 0 at clamped index -> no-op

    float v = features[(size_t)p * NF + f];
    size_t idx = (((size_t)gx * BOX + gy) * BOX + gz) * NF + f;
    atomicAdd(grid + idx, v);  // device-scope by default on CDNA
}

extern "C" void kernel_launch(void* const* d_in, const int* in_sizes, int n_in,
                              void* d_out, int out_size, void* d_ws, size_t ws_size,
                              hipStream_t stream) {
    const float* coords   = (const float*)d_in[0];  // [B,N,3] fp32
    const float* features = (const float*)d_in[1];  // [B,N,F] fp32
    float* out = (float*)d_out;                     // [B,71,71,71,F] fp32

    // out_size == 366,500,864 (logical output BYTES). The persistent 1.466 GB
    // fillBufferAligned dispatches in rocprof are the HARNESS poisoning a
    // 4x-overallocated buffer, not us: our R1 memset of exactly out_size bytes
    // verified (absmax 0.0) while the 1.466 GB fills persisted.
    // Our own named zeroing kernel gives rocprof attribution + slice-0 cache
    // priming.
    zero_grid<<<2048, 256, 0, stream>>>((f32x4*)out);

    int total_points = in_sizes[0] / 3;             // B*N = 131072
    int total_threads = total_points * NF;
    int blocks = (total_threads + 255) / 256;
    MakeGrid_scatter_kernel<<<blocks, 256, 0, stream>>>(coords, features, out, total_points);
}

// Round 4
// 383.259 us; speedup vs baseline: 1.0319x; 1.0319x over previous
//
#include <hip/hip_runtime.h>

#define BOX 71
#define NF 32
#define MAX_DIST_F 35.0f

// Output: [B=8, 71,71,71, F=32] fp32. Reference scatters EVERY batch into
// batch slice 0 => slices 1..7 are always all-zero; all atomics land in the
// first 45.8 MB.
#define SLICE_FLOATS (BOX * BOX * BOX * NF)          // 11,453,152 floats
#define SLICE_BYTES  ((size_t)SLICE_FLOATS * 4)      // 45,812,608 bytes
#define REST_F4      ((7 * SLICE_FLOATS) / 4)        // 20,043,016 float4s

typedef float f32x4 __attribute__((ext_vector_type(4)));

// Fused kernel: blocks with blockIdx%5==0 zero slices 1..7 (320.7 MB,
// BW-bound); the rest scatter (atomic-latency-bound, ~13 MB of traffic).
// Interleaving roles by blockIdx%5 makes both run concurrently across the
// dispatch sequence, overlapping the big zero-fill with the scatter.
// Regions are disjoint (zero: slices 1..7; scatter: slice 0) -> no ordering
// hazard. Slice 0 itself is zeroed by a small memset BEFORE this kernel.
__global__ __launch_bounds__(256) void fused_zero_scatter(
    const float* __restrict__ coords,
    const float* __restrict__ features,
    float* __restrict__ grid,
    int total_points,
    int nzb)                       // number of zeroing blocks actually launched
{
    if (blockIdx.x % 5 == 0) {
        // ---- zero slices 1..7 with plain float4 stores (no NT: R3 showed the
        // NT/branchy variant was slower than a straight fill) ----
        int zid = blockIdx.x / 5;                    // dense 0..nzb-1
        f32x4* rest = (f32x4*)(grid + SLICE_FLOATS); // 16B-aligned (45,812,608 % 16 == 0)
        const f32x4 z = {0.f, 0.f, 0.f, 0.f};
        int stride = nzb * 256;
        for (int i = zid * 256 + (int)threadIdx.x; i < REST_F4; i += stride)
            rest[i] = z;
    } else {
        // ---- scatter: one 32-lane group per point; lane f handles feature f ----
        int sid = blockIdx.x - 1 - blockIdx.x / 5;   // dense 0..(#scatter blocks-1)
        int t = sid * 256 + (int)threadIdx.x;
        int p = t >> 5;          // point index
        int f = t & 31;          // feature index
        if (p >= total_points) return;

        // All 32 lanes of the group load the same 3 coords (cache broadcast).
        float cx = coords[p * 3 + 0];
        float cy = coords[p * 3 + 1];
        float cz = coords[p * 3 + 2];

        // jnp.round = round-half-to-even; rintf matches (default RNE mode).
        // GRID_RES = 1.0 so (c + 35.0f)/1.0f == c + 35.0f exactly.
        int gx = (int)rintf(cx + MAX_DIST_F);
        int gy = (int)rintf(cy + MAX_DIST_F);
        int gz = (int)rintf(cz + MAX_DIST_F);

        bool in_box = (gx >= 0) & (gx < BOX) &
                      (gy >= 0) & (gy < BOX) &
                      (gz >= 0) & (gz < BOX);
        if (!in_box) return;     // reference adds 0 at clamped index -> no-op

        float v = features[(size_t)p * NF + f];
        size_t idx = (((size_t)gx * BOX + gy) * BOX + gz) * NF + f;
        atomicAdd(grid + idx, v);  // device-scope by default on CDNA
    }
}

extern "C" void kernel_launch(void* const* d_in, const int* in_sizes, int n_in,
                              void* d_out, int out_size, void* d_ws, size_t ws_size,
                              hipStream_t stream) {
    const float* coords   = (const float*)d_in[0];  // [B,N,3] fp32
    const float* features = (const float*)d_in[1];  // [B,N,F] fp32
    float* out = (float*)d_out;                     // [B,71,71,71,F] fp32

    // Model (R0-R3 differentials): the ~239us 1.466GB fillBufferAligned per
    // iteration is the HARNESS poison of the overallocated output, serialized
    // before our work in the timed window. Our controllable span is
    // zero(366MB)+scatter. Scatter only needs slice 0 zeroed:
    //   1) memset slice 0 only (45.8 MB, ~7us)
    //   2) fused kernel: zero slices 1..7 (320MB) OVERLAPPED with the scatter.
    hipMemsetAsync(out, 0, SLICE_BYTES, stream);

    int total_points   = in_sizes[0] / 3;                    // B*N = 131072
    int scatter_blocks = (total_points * NF + 255) / 256;    // 16384
    int nzb            = 4096;                               // ~1/5 of blocks zero
    int total_blocks   = scatter_blocks + nzb;               // 20480
    // Mapping check: #(bid%5==0) in [0,total_blocks) must equal nzb so the
    // grid-stride zero loop covers REST_F4 and sid is dense. 20480/5 == 4096.
    fused_zero_scatter<<<total_blocks, 256, 0, stream>>>(
        coords, features, out, total_points, nzb);
}

// Round 5
// 328.317 us; speedup vs baseline: 1.2045x; 1.1673x over previous
//
#include <hip/hip_runtime.h>

#define BOX 71
#define NF 32
#define MAX_DIST_F 35.0f

// ===========================================================================
// Session model (R0-R4 differentials):
//  - Harness poisons the 4x-overallocated output (1.466 GB fill, ~239 us)
//    INSIDE the timed window, every iteration. Untouchable floor.
//  - Our span floor = full 366 MB zero (~58 us, compulsory: poison re-dirties
//    everything) + scatter (~31 us).
//  - The FULL-buffer memset is load-bearing for scatter speed: writing the
//    320 MB of slices 1..7 AFTER slice 0 evicts slice-0 lines from all
//    per-XCD L2s, so the device-scope atomics hit clean lines at the
//    memory-side cache (fast path). Variants that left slice 0 dirty in L2
//    (R4: slice-0-only memset + fused zero; R3: NT-store zero) regressed
//    +55..+67 us from cross-XCD coherence on the atomic path. Do NOT "optimize"
//    the memset into something partial/fused/NT.
// ===========================================================================

// One 32-lane group per point: lane f handles feature f.
// features layout [B,N,F] -> consecutive lanes read consecutive floats (coalesced).
// atomic target grid[0, x, y, z, f] -> 32 consecutive floats per point (coalesced burst).
__global__ __launch_bounds__(256) void MakeGrid_scatter_kernel(
    const float* __restrict__ coords,
    const float* __restrict__ features,
    float* __restrict__ grid,
    int total_points)
{
    int t = blockIdx.x * blockDim.x + threadIdx.x;
    int p = t >> 5;          // point index
    int f = t & 31;          // feature index
    if (p >= total_points) return;

    // All 32 lanes of the group load the same 3 coords (cache broadcast).
    float cx = coords[p * 3 + 0];
    float cy = coords[p * 3 + 1];
    float cz = coords[p * 3 + 2];

    // jnp.round = round-half-to-even; rintf matches (default RNE rounding mode).
    // GRID_RES = 1.0 so (c + 35.0f) / 1.0f == c + 35.0f exactly.
    int gx = (int)rintf(cx + MAX_DIST_F);
    int gy = (int)rintf(cy + MAX_DIST_F);
    int gz = (int)rintf(cz + MAX_DIST_F);

    bool in_box = (gx >= 0) & (gx < BOX) &
                  (gy >= 0) & (gy < BOX) &
                  (gz >= 0) & (gz < BOX);
    if (!in_box) return;     // reference adds 0 at clamped index -> no-op

    float v = features[(size_t)p * NF + f];
    size_t idx = (((size_t)gx * BOX + gy) * BOX + gz) * NF + f;
    // unsafeAtomicAdd -> hardware global_atomic_add_f32 (hipcc otherwise may
    // emit a CAS loop for fp32 global atomics). Bit-identical to CAS for
    // normal-range values (differs only in denormal flushing; features are
    // ~N(0,1)). Device scope -> correct across XCDs.
#if defined(__AMDGCN__)
    unsafeAtomicAdd(grid + idx, v);
#else
    atomicAdd(grid + idx, v);
#endif
}

extern "C" void kernel_launch(void* const* d_in, const int* in_sizes, int n_in,
                              void* d_out, int out_size, void* d_ws, size_t ws_size,
                              hipStream_t stream) {
    const float* coords   = (const float*)d_in[0];  // [B,N,3] fp32
    const float* features = (const float*)d_in[1];  // [B,N,F] fp32
    float* out = (float*)d_out;                     // [B,71,71,71,F] fp32

    // out_size is the logical output BYTE count (366,500,864). Zero exactly
    // that, in one rocclr fill (measured ~6.1 TB/s). See model note above:
    // full-size + store-order (slice 0 first, evicted by slices 1..7) is what
    // keeps the scatter's atomics on the fast memory-side path.
    hipMemsetAsync(out, 0, (size_t)out_size, stream);

    int total_points = in_sizes[0] / 3;             // B*N = 131072
    int total_threads = total_points * NF;
    int blocks = (total_threads + 255) / 256;
    MakeGrid_scatter_kernel<<<blocks, 256, 0, stream>>>(coords, features, out, total_points);
}